// Round 3
// baseline (111.636 us; speedup 1.0000x reference)
//
#include <hip/hip_runtime.h>

#define BB 8
#define NN 2048
#define MM 2048

constexpr int TN = 256; // n-tile
constexpr int TM = 256; // m-tile

__global__ __launch_bounds__(256) void init_kernel(unsigned* __restrict__ src_bits,
                                                   unsigned* __restrict__ dst_bits) {
    int i = blockIdx.x * blockDim.x + threadIdx.x;
    const unsigned INF_BITS = 0x7F800000u;
    if (i < BB * NN) src_bits[i] = INF_BITS;
    if (i < BB * MM) dst_bits[i] = INF_BITS;
}

__global__ __launch_bounds__(256) void dist_kernel(const float* __restrict__ src,
                                                   const float* __restrict__ tgt,
                                                   const float* __restrict__ mask,
                                                   unsigned* __restrict__ src_bits,
                                                   unsigned* __restrict__ dst_bits) {
    __shared__ float sx[TN], sy[TN], sz[TN];
    __shared__ float tx[TM], ty[TM], tz[TM], tmsk[TM];

    const int b  = blockIdx.z;
    const int n0 = blockIdx.y * TN;
    const int m0 = blockIdx.x * TM;
    const int t  = threadIdx.x;

    // Stage tiles in LDS (thread t loads point t; 3 floats each)
    {
        const float* sp = src + ((size_t)b * NN + n0) * 3;
        sx[t] = sp[t * 3 + 0];
        sy[t] = sp[t * 3 + 1];
        sz[t] = sp[t * 3 + 2];
        const float* tp = tgt + ((size_t)b * MM + m0) * 3;
        tx[t] = tp[t * 3 + 0];
        ty[t] = tp[t * 3 + 1];
        tz[t] = tp[t * 3 + 2];
        tmsk[t] = mask[(size_t)b * MM + m0 + t];
    }
    __syncthreads();

    const float INF = __int_as_float(0x7F800000);

    // Phase A: thread t owns n = n0+t; min over masked m in tile.
    // (reference's min(d - mask*max)+max == min over masked m of d, exactly)
    {
        const float ax = sx[t], ay = sy[t], az = sz[t];
        float mn = INF;
#pragma unroll 8
        for (int j = 0; j < TM; ++j) {
            float d = fabsf(ax - tx[j]) + fabsf(ay - ty[j]) + fabsf(az - tz[j]);
            float dm = (tmsk[j] != 0.0f) ? d : INF;
            mn = fminf(mn, dm);
        }
        atomicMin(&src_bits[(size_t)b * NN + n0 + t], __float_as_uint(mn));
    }

    // Phase B: thread t owns m = m0+t; min over all n in tile.
    {
        const float bx = tx[t], by = ty[t], bz = tz[t];
        float mn = INF;
#pragma unroll 8
        for (int j = 0; j < TN; ++j) {
            float d = fabsf(bx - sx[j]) + fabsf(by - sy[j]) + fabsf(bz - sz[j]);
            mn = fminf(mn, d);
        }
        atomicMin(&dst_bits[(size_t)b * MM + m0 + t], __float_as_uint(mn));
    }
}

__global__ __launch_bounds__(1024) void reduce_kernel(const unsigned* __restrict__ src_bits,
                                                      const unsigned* __restrict__ dst_bits,
                                                      const float* __restrict__ mask,
                                                      float* __restrict__ out) {
    const int t = threadIdx.x;
    float s_src = 0.f, s_dst = 0.f, s_msk = 0.f;

    for (int i = t; i < BB * NN; i += 1024) s_src += __uint_as_float(src_bits[i]);
    for (int i = t; i < BB * MM; i += 1024) {
        float mk = mask[i];
        s_dst += __uint_as_float(dst_bits[i]) * mk;
        s_msk += mk;
    }

    // wave (64-lane) shuffle reduce
    for (int off = 32; off > 0; off >>= 1) {
        s_src += __shfl_down(s_src, off);
        s_dst += __shfl_down(s_dst, off);
        s_msk += __shfl_down(s_msk, off);
    }

    __shared__ float w0[16], w1[16], w2[16];
    const int lane = t & 63, wid = t >> 6;
    if (lane == 0) { w0[wid] = s_src; w1[wid] = s_dst; w2[wid] = s_msk; }
    __syncthreads();

    if (t == 0) {
        float a = 0.f, bsum = 0.f, c = 0.f;
        for (int i = 0; i < 16; ++i) { a += w0[i]; bsum += w1[i]; c += w2[i]; }
        out[0] = a / (float)(BB * NN); // loss_src = mean(src2dst)
        out[1] = bsum / c;             // loss_dst = sum(dst2src*mask)/sum(mask)
    }
}

extern "C" void kernel_launch(void* const* d_in, const int* in_sizes, int n_in,
                              void* d_out, int out_size, void* d_ws, size_t ws_size,
                              hipStream_t stream) {
    const float* src  = (const float*)d_in[0]; // [B, N, 3]
    const float* tgt  = (const float*)d_in[1]; // [B, M, 3]
    const float* mask = (const float*)d_in[2]; // [B, M]
    float* out = (float*)d_out;                // {loss_src, loss_dst}

    unsigned* src_bits = (unsigned*)d_ws;          // B*N uints
    unsigned* dst_bits = src_bits + (size_t)BB * NN; // B*M uints

    init_kernel<<<(BB * NN + 255) / 256, 256, 0, stream>>>(src_bits, dst_bits);

    dim3 grid(MM / TM, NN / TN, BB); // (8, 8, 8) = 512 blocks
    dist_kernel<<<grid, 256, 0, stream>>>(src, tgt, mask, src_bits, dst_bits);

    reduce_kernel<<<1, 1024, 0, stream>>>(src_bits, dst_bits, mask, out);
}

// Round 4
// 93.073 us; speedup vs baseline: 1.1994x; 1.1994x over previous
//
#include <hip/hip_runtime.h>

#define BB 8
#define NN 2048
#define MM 2048
#define TS 128          // tile edge (both dims)
#define NT_M (MM / TS)  // 16 target tiles
#define NT_N (NN / TS)  // 16 source tiles

struct Accums { float ssum, dsum, msum; unsigned cnt; };

// Grid (NT_M, NT_N, BB) = (16,16,8) = 2048 blocks, 256 threads.
// Each block: stage 128 src + 128 tgt points as float4 in LDS, compute both
// directional partial mins; two threads (halves) split each point's j-loop
// and combine via LDS; write one partial min per point per tile (no atomics).
__global__ __launch_bounds__(256) void dist_kernel(const float* __restrict__ src,
                                                   const float* __restrict__ tgt,
                                                   const float* __restrict__ mask,
                                                   float* __restrict__ spart,
                                                   float* __restrict__ dpart,
                                                   Accums* __restrict__ acc) {
    __shared__ float4 ss[TS];   // src points (w = 0)
    __shared__ float4 st[TS];   // tgt points (w = mask ? 0 : +INF)
    __shared__ float pA[TS];
    __shared__ float pB[TS];

    const int b  = blockIdx.z;
    const int n0 = blockIdx.y * TS;
    const int m0 = blockIdx.x * TS;
    const int t  = threadIdx.x;
    const float INF = __int_as_float(0x7F800000);

    // Zero the cross-kernel accumulators once per launch (stream-ordered
    // before reduce_kernel; ws is re-poisoned 0xAA before every timed call).
    if (blockIdx.x == 0 && blockIdx.y == 0 && blockIdx.z == 0 && t == 0) {
        acc->ssum = 0.f; acc->dsum = 0.f; acc->msum = 0.f; acc->cnt = 0u;
    }

    if (t < TS) {
        const float* sp = src + ((size_t)b * NN + n0 + t) * 3;
        ss[t] = make_float4(sp[0], sp[1], sp[2], 0.f);
    } else {
        const int j = t - TS;
        const float* tp = tgt + ((size_t)b * MM + m0 + j) * 3;
        const float mk = mask[(size_t)b * MM + m0 + j];
        // masked-out target -> +INF penalty: d + INF = INF, excluded from min.
        st[j] = make_float4(tp[0], tp[1], tp[2], (mk != 0.f) ? 0.f : INF);
    }
    __syncthreads();

    const int p  = t & (TS - 1); // point within tile
    const int h  = t >> 7;       // which half of the j-loop
    const int j0 = h * (TS / 2);

    // Phase A: src2dst — min over masked targets in this tile.
    {
        const float4 a = ss[p];
        float mn = INF;
#pragma unroll 8
        for (int j = j0; j < j0 + TS / 2; ++j) {
            const float4 w = st[j];
            const float d = fabsf(a.x - w.x) + fabsf(a.y - w.y) + fabsf(a.z - w.z) + w.w;
            mn = fminf(mn, d);
        }
        if (h == 0) pA[p] = mn;
        __syncthreads();
        if (h == 1)
            spart[((size_t)(b * NT_M + blockIdx.x)) * NN + n0 + p] = fminf(pA[p], mn);
    }

    // Phase B: dst2src — min over all sources in this tile.
    {
        const float4 a = st[p];
        float mn = INF;
#pragma unroll 8
        for (int j = j0; j < j0 + TS / 2; ++j) {
            const float4 w = ss[j];
            const float d = fabsf(a.x - w.x) + fabsf(a.y - w.y) + fabsf(a.z - w.z);
            mn = fminf(mn, d);
        }
        if (h == 0) pB[p] = mn;
        __syncthreads();
        if (h == 1)
            dpart[((size_t)(b * NT_N + blockIdx.y)) * MM + m0 + p] = fminf(pB[p], mn);
    }
}

// 64 blocks x 256 threads = 16384 threads: one (b,n) and one (b,m) column each.
// Tile-min + masked sums -> block reduce -> atomicAdd; last block finalizes.
__global__ __launch_bounds__(256) void reduce_kernel(const float* __restrict__ spart,
                                                     const float* __restrict__ dpart,
                                                     const float* __restrict__ mask,
                                                     Accums* __restrict__ acc,
                                                     float* __restrict__ out) {
    const int t   = threadIdx.x;
    const int idx = blockIdx.x * 256 + t;   // [0, 16384)
    const int b   = idx >> 11;
    const int q   = idx & (NN - 1);

    const float INF = __int_as_float(0x7F800000);
    float smin = INF, dmin = INF;
#pragma unroll
    for (int k = 0; k < NT_M; ++k)
        smin = fminf(smin, spart[((size_t)(b * NT_M + k)) * NN + q]);
#pragma unroll
    for (int k = 0; k < NT_N; ++k)
        dmin = fminf(dmin, dpart[((size_t)(b * NT_N + k)) * MM + q]);

    const float mk = mask[(size_t)b * MM + q];
    float vs = smin, vd = dmin * mk, vm = mk;

    for (int off = 32; off; off >>= 1) {
        vs += __shfl_down(vs, off);
        vd += __shfl_down(vd, off);
        vm += __shfl_down(vm, off);
    }

    __shared__ float w0[4], w1[4], w2[4];
    const int lane = t & 63, wid = t >> 6;
    if (lane == 0) { w0[wid] = vs; w1[wid] = vd; w2[wid] = vm; }
    __syncthreads();

    if (t == 0) {
        float a = 0.f, c = 0.f, d = 0.f;
        for (int i = 0; i < 4; ++i) { a += w0[i]; c += w1[i]; d += w2[i]; }
        atomicAdd(&acc->ssum, a);
        atomicAdd(&acc->dsum, c);
        atomicAdd(&acc->msum, d);
        __threadfence();
        const unsigned old = atomicAdd(&acc->cnt, 1u);
        if (old == gridDim.x - 1) {   // last block done: all adds visible
            const float S = atomicAdd(&acc->ssum, 0.f);
            const float D = atomicAdd(&acc->dsum, 0.f);
            const float Mm = atomicAdd(&acc->msum, 0.f);
            out[0] = S / (float)(BB * NN); // loss_src = mean(src2dst)
            out[1] = D / Mm;               // loss_dst = sum(dst2src*mask)/sum(mask)
        }
    }
}

extern "C" void kernel_launch(void* const* d_in, const int* in_sizes, int n_in,
                              void* d_out, int out_size, void* d_ws, size_t ws_size,
                              hipStream_t stream) {
    const float* src  = (const float*)d_in[0]; // [B, N, 3]
    const float* tgt  = (const float*)d_in[1]; // [B, M, 3]
    const float* mask = (const float*)d_in[2]; // [B, M]
    float* out = (float*)d_out;

    float*  spart = (float*)d_ws;                             // B*NT_M*NN floats (1 MB)
    float*  dpart = spart + (size_t)BB * NT_M * NN;           // B*NT_N*MM floats (1 MB)
    Accums* acc   = (Accums*)(dpart + (size_t)BB * NT_N * MM);

    dim3 grid(NT_M, NT_N, BB); // (16,16,8) = 2048 blocks
    dist_kernel<<<grid, 256, 0, stream>>>(src, tgt, mask, spart, dpart, acc);
    reduce_kernel<<<64, 256, 0, stream>>>(spart, dpart, mask, acc, out);
}

// Round 9
// 71.600 us; speedup vs baseline: 1.5592x; 1.2999x over previous
//
#include <hip/hip_runtime.h>

#define BB 8
#define NN 2048
#define MM 2048
#define TS 128          // tile edge (both dims)
#define NT_M (MM / TS)  // 16 target tiles
#define NT_N (NN / TS)  // 16 source tiles

struct Accums { float ssum, dsum, msum; unsigned cnt; };

// Grid (NT_M, NT_N, BB) = (16,16,8) = 2048 blocks, 256 threads (8 blocks/CU).
// Register blocking: thread owns 4 points (o, o+32, o+64, o+96), covers j-group
// g = t>>5 (16 j's). One ds_read_b128 feeds 4 distance evals.
__global__ __launch_bounds__(256) void dist_kernel(const float* __restrict__ src,
                                                   const float* __restrict__ tgt,
                                                   const float* __restrict__ mask,
                                                   float* __restrict__ spart,
                                                   float* __restrict__ dpart,
                                                   Accums* __restrict__ acc) {
    __shared__ float4 ss[TS];      // src points (w unused)
    __shared__ float4 st[TS];      // tgt points (w = mask ? 0 : +INF)
    __shared__ float pA[8][TS];    // per-j-group partial mins, src2dst
    __shared__ float pB[8][TS];    // per-j-group partial mins, dst2src

    const int b  = blockIdx.z;
    const int n0 = blockIdx.y * TS;
    const int m0 = blockIdx.x * TS;
    const int t  = threadIdx.x;
    const float INF = __int_as_float(0x7F800000);

    if (blockIdx.x == 0 && blockIdx.y == 0 && blockIdx.z == 0 && t == 0) {
        acc->ssum = 0.f; acc->dsum = 0.f; acc->msum = 0.f; acc->cnt = 0u;
    }

    if (t < TS) {
        const float* sp = src + ((size_t)b * NN + n0 + t) * 3;
        ss[t] = make_float4(sp[0], sp[1], sp[2], 0.f);
    } else {
        const int j = t - TS;
        const float* tp = tgt + ((size_t)b * MM + m0 + j) * 3;
        const float mk = mask[(size_t)b * MM + m0 + j];
        st[j] = make_float4(tp[0], tp[1], tp[2], (mk != 0.f) ? 0.f : INF);
    }
    __syncthreads();

    const int o = t & 31;   // owner: points o, o+32, o+64, o+96
    const int g = t >> 5;   // j-group: j in [g*16, g*16+16)

    // Phase A: src2dst — min over masked targets (w.w = +INF excludes).
    {
        const float4 a0 = ss[o], a1 = ss[o + 32], a2 = ss[o + 64], a3 = ss[o + 96];
        float m0_ = INF, m1_ = INF, m2_ = INF, m3_ = INF;
#pragma unroll
        for (int jj = 0; jj < 16; ++jj) {
            const float4 w = st[g * 16 + jj];
            m0_ = fminf(m0_, fabsf(a0.x - w.x) + fabsf(a0.y - w.y) + fabsf(a0.z - w.z) + w.w);
            m1_ = fminf(m1_, fabsf(a1.x - w.x) + fabsf(a1.y - w.y) + fabsf(a1.z - w.z) + w.w);
            m2_ = fminf(m2_, fabsf(a2.x - w.x) + fabsf(a2.y - w.y) + fabsf(a2.z - w.z) + w.w);
            m3_ = fminf(m3_, fabsf(a3.x - w.x) + fabsf(a3.y - w.y) + fabsf(a3.z - w.z) + w.w);
        }
        pA[g][o] = m0_; pA[g][o + 32] = m1_; pA[g][o + 64] = m2_; pA[g][o + 96] = m3_;
    }

    // Phase B: dst2src — min over all sources (xyz only; w ignored).
    {
        const float4 b0 = st[o], b1 = st[o + 32], b2 = st[o + 64], b3 = st[o + 96];
        float m0_ = INF, m1_ = INF, m2_ = INF, m3_ = INF;
#pragma unroll
        for (int jj = 0; jj < 16; ++jj) {
            const float4 w = ss[g * 16 + jj];
            m0_ = fminf(m0_, fabsf(b0.x - w.x) + fabsf(b0.y - w.y) + fabsf(b0.z - w.z));
            m1_ = fminf(m1_, fabsf(b1.x - w.x) + fabsf(b1.y - w.y) + fabsf(b1.z - w.z));
            m2_ = fminf(m2_, fabsf(b2.x - w.x) + fabsf(b2.y - w.y) + fabsf(b2.z - w.z));
            m3_ = fminf(m3_, fabsf(b3.x - w.x) + fabsf(b3.y - w.y) + fabsf(b3.z - w.z));
        }
        pB[g][o] = m0_; pB[g][o + 32] = m1_; pB[g][o + 64] = m2_; pB[g][o + 96] = m3_;
    }

    __syncthreads();

    // Combine 8 j-group partials per point; halves of the block split A/B.
    if (t < TS) {
        float mn = pA[0][t];
#pragma unroll
        for (int k = 1; k < 8; ++k) mn = fminf(mn, pA[k][t]);
        spart[((size_t)(b * NT_M + blockIdx.x)) * NN + n0 + t] = mn;
    } else {
        const int p = t - TS;
        float mn = pB[0][p];
#pragma unroll
        for (int k = 1; k < 8; ++k) mn = fminf(mn, pB[k][p]);
        dpart[((size_t)(b * NT_N + blockIdx.y)) * MM + m0 + p] = mn;
    }
}

// 64 blocks x 256 threads = 16384 threads: one (b,n) and one (b,m) column each.
__global__ __launch_bounds__(256) void reduce_kernel(const float* __restrict__ spart,
                                                     const float* __restrict__ dpart,
                                                     const float* __restrict__ mask,
                                                     Accums* __restrict__ acc,
                                                     float* __restrict__ out) {
    const int t   = threadIdx.x;
    const int idx = blockIdx.x * 256 + t;   // [0, 16384)
    const int b   = idx >> 11;
    const int q   = idx & (NN - 1);

    const float INF = __int_as_float(0x7F800000);
    float smin = INF, dmin = INF;
#pragma unroll
    for (int k = 0; k < NT_M; ++k)
        smin = fminf(smin, spart[((size_t)(b * NT_M + k)) * NN + q]);
#pragma unroll
    for (int k = 0; k < NT_N; ++k)
        dmin = fminf(dmin, dpart[((size_t)(b * NT_N + k)) * MM + q]);

    const float mk = mask[(size_t)b * MM + q];
    float vs = smin, vd = dmin * mk, vm = mk;

    for (int off = 32; off; off >>= 1) {
        vs += __shfl_down(vs, off);
        vd += __shfl_down(vd, off);
        vm += __shfl_down(vm, off);
    }

    __shared__ float w0[4], w1[4], w2[4];
    const int lane = t & 63, wid = t >> 6;
    if (lane == 0) { w0[wid] = vs; w1[wid] = vd; w2[wid] = vm; }
    __syncthreads();

    if (t == 0) {
        float a = 0.f, c = 0.f, d = 0.f;
        for (int i = 0; i < 4; ++i) { a += w0[i]; c += w1[i]; d += w2[i]; }
        atomicAdd(&acc->ssum, a);
        atomicAdd(&acc->dsum, c);
        atomicAdd(&acc->msum, d);
        __threadfence();
        const unsigned old = atomicAdd(&acc->cnt, 1u);
        if (old == gridDim.x - 1) {
            const float S  = atomicAdd(&acc->ssum, 0.f);
            const float D  = atomicAdd(&acc->dsum, 0.f);
            const float Mm = atomicAdd(&acc->msum, 0.f);
            out[0] = S / (float)(BB * NN); // loss_src = mean(src2dst)
            out[1] = D / Mm;               // loss_dst = sum(dst2src*mask)/sum(mask)
        }
    }
}

extern "C" void kernel_launch(void* const* d_in, const int* in_sizes, int n_in,
                              void* d_out, int out_size, void* d_ws, size_t ws_size,
                              hipStream_t stream) {
    const float* src  = (const float*)d_in[0]; // [B, N, 3]
    const float* tgt  = (const float*)d_in[1]; // [B, M, 3]
    const float* mask = (const float*)d_in[2]; // [B, M]
    float* out = (float*)d_out;

    float*  spart = (float*)d_ws;                             // B*NT_M*NN floats (1 MB)
    float*  dpart = spart + (size_t)BB * NT_M * NN;           // B*NT_N*MM floats (1 MB)
    Accums* acc   = (Accums*)(dpart + (size_t)BB * NT_N * MM);

    dim3 grid(NT_M, NT_N, BB); // (16,16,8) = 2048 blocks
    dist_kernel<<<grid, 256, 0, stream>>>(src, tgt, mask, spart, dpart, acc);
    reduce_kernel<<<64, 256, 0, stream>>>(spart, dpart, mask, acc, out);
}